// Round 3
// baseline (315.360 us; speedup 1.0000x reference)
//
#include <hip/hip_runtime.h>

#define NN 50000
#define NE 800000
#define FDIM 64
#define SCAN_T 1024
#define CHUNK ((NN + SCAN_T - 1) / SCAN_T)   // 49

// ---------------------------------------------------------------- degree ----
__global__ void k_degree(const int* __restrict__ col,
                         int* __restrict__ deg, int E) {
    int i = blockIdx.x * blockDim.x + threadIdx.x;
    int stride = gridDim.x * blockDim.x;
    for (; i < E; i += stride) atomicAdd(&deg[col[i]], 1);
}

// ------------------------- exclusive scan of deg -> rowptr; also rdeg -------
__global__ __launch_bounds__(SCAN_T) void k_scan(const int* __restrict__ deg,
                                                 int* __restrict__ rowptr,
                                                 float* __restrict__ rdeg) {
    __shared__ int part[SCAN_T];
    int t = threadIdx.x;
    int base = t * CHUNK;
    int s = 0;
    for (int i = 0; i < CHUNK; ++i) {
        int idx = base + i;
        if (idx < NN) s += deg[idx];
    }
    part[t] = s;
    __syncthreads();
    // Hillis-Steele inclusive scan over 1024 partials
    for (int off = 1; off < SCAN_T; off <<= 1) {
        int v = (t >= off) ? part[t - off] : 0;
        __syncthreads();
        part[t] += v;
        __syncthreads();
    }
    int run = (t > 0) ? part[t - 1] : 0;   // exclusive prefix
    for (int i = 0; i < CHUNK; ++i) {
        int idx = base + i;
        if (idx < NN) {
            rowptr[idx] = run;
            int d = deg[idx];
            run += d;
            rdeg[idx] = (d > 0) ? rsqrtf((float)d) : 0.f;
        }
    }
    if (t == SCAN_T - 1) rowptr[NN] = run;   // == NE
}

// -------------------------------- z = rdeg[r] * (x @ W^T)[r] ----------------
__global__ void k_gemm(const float* __restrict__ x, const float* __restrict__ W,
                       const float* __restrict__ rdeg,
                       float* __restrict__ z, int n) {
    __shared__ float Wl[FDIM * (FDIM + 1)];
    for (int i = threadIdx.x; i < FDIM * FDIM; i += blockDim.x) {
        int o = i / FDIM, k = i % FDIM;
        Wl[o * (FDIM + 1) + k] = W[i];
    }
    __syncthreads();

    int lane  = threadIdx.x & 63;
    int wave  = (blockIdx.x * blockDim.x + threadIdx.x) >> 6;
    int nwave = (gridDim.x * blockDim.x) >> 6;

    for (int r = wave; r < n; r += nwave) {
        float xv = x[r * FDIM + lane];
        float acc = 0.f;
#pragma unroll
        for (int k = 0; k < FDIM; ++k) {
            float a = __shfl(xv, k, 64);
            acc += a * Wl[lane * (FDIM + 1) + k];
        }
        z[r * FDIM + lane] = rdeg[r] * acc;
    }
}

// ------------------------------- bucket-fill CSR ----------------------------
__global__ void k_bucket(const int* __restrict__ rowi, const int* __restrict__ coli,
                         const int* __restrict__ rowptr, int* __restrict__ cursor,
                         int* __restrict__ erow, int E) {
    int i = blockIdx.x * blockDim.x + threadIdx.x;
    int stride = gridDim.x * blockDim.x;
    for (; i < E; i += stride) {
        int c = coli[i];
        int p = atomicAdd(&cursor[c], 1);
        erow[rowptr[c] + p] = rowi[i];
    }
}

// --------------------- gather: out[c] = rdeg[c]*sum z[r] + b ----------------
__global__ void k_gather(const int* __restrict__ rowptr, const int* __restrict__ erow,
                         const float* __restrict__ z, const float* __restrict__ rdeg,
                         const float* __restrict__ b, float* __restrict__ out) {
    int lane = threadIdx.x & 63;
    int node = (int)((blockIdx.x * blockDim.x + threadIdx.x) >> 6);
    if (node >= NN) return;
    int s = rowptr[node], e = rowptr[node + 1];
    float acc = 0.f;
    for (int base = s; base < e; base += 64) {
        int cnt = min(64, e - base);
        int idx = (lane < cnt) ? erow[base + lane] : 0;
        for (int j = 0; j < cnt; ++j) {
            int r = __shfl(idx, j, 64);
            acc += z[r * FDIM + lane];
        }
    }
    out[node * FDIM + lane] = rdeg[node] * acc + b[lane];
}

// ---------------------------------------------------------------------------
extern "C" void kernel_launch(void* const* d_in, const int* in_sizes, int n_in,
                              void* d_out, int out_size, void* d_ws, size_t ws_size,
                              hipStream_t stream) {
    const float* x   = (const float*)d_in[0];
    // d_in[1] = x0 (unused: use_init=False)
    const int*   ei  = (const int*)d_in[2];   // harness stores integers as int32
    const float* W_w = (const float*)d_in[3];
    const float* W_b = (const float*)d_in[4];
    float*       out = (float*)d_out;

    const int* rowi = ei;        // edge_index[0]
    const int* coli = ei + NE;   // edge_index[1]

    // workspace layout (256B-aligned chunks):
    char* p = (char*)d_ws;
    auto alloc = [&](size_t bytes) {
        char* r = p;
        p += (bytes + 255) & ~(size_t)255;
        return r;
    };
    int*   deg    = (int*)alloc(NN * sizeof(int));
    int*   cursor = (int*)alloc(NN * sizeof(int));
    int*   rowptr = (int*)alloc((NN + 1) * sizeof(int));
    float* rdeg   = (float*)alloc(NN * sizeof(float));
    int*   erow   = (int*)alloc((size_t)NE * sizeof(int));
    float* z      = (float*)alloc((size_t)NN * FDIM * sizeof(float));

    hipMemsetAsync(deg, 0, NN * sizeof(int), stream);
    hipMemsetAsync(cursor, 0, NN * sizeof(int), stream);

    k_degree<<<2048, 256, 0, stream>>>(coli, deg, NE);
    k_scan<<<1, SCAN_T, 0, stream>>>(deg, rowptr, rdeg);
    k_gemm<<<2048, 256, 0, stream>>>(x, W_w, rdeg, z, NN);
    k_bucket<<<2048, 256, 0, stream>>>(rowi, coli, rowptr, cursor, erow, NE);
    k_gather<<<(NN + 3) / 4, 256, 0, stream>>>(rowptr, erow, z, rdeg, W_b, out);
}

// Round 4
// 194.852 us; speedup vs baseline: 1.6185x; 1.6185x over previous
//
#include <hip/hip_runtime.h>

#define NN 50000
#define NE 800000
#define FDIM 64

// ---------------------------------------------------------------- degree ----
__global__ void k_degree(const int* __restrict__ col,
                         int* __restrict__ deg, int E) {
    int i = blockIdx.x * blockDim.x + threadIdx.x;
    int stride = gridDim.x * blockDim.x;
    for (; i < E; i += stride) atomicAdd(&deg[col[i]], 1);
}

// ------------- CSR range reservation (order-free, replaces prefix scan) -----
// rowptr[i] = disjoint range start of size deg[i]; also rdeg[i] = rsqrt(deg).
// Wave-level prefix so only one global atomic per wave.
__global__ void k_offsets(const int* __restrict__ deg,
                          int* __restrict__ rowptr,
                          float* __restrict__ rdeg,
                          int* __restrict__ gcount) {
    int i = blockIdx.x * blockDim.x + threadIdx.x;
    int lane = threadIdx.x & 63;
    int d = (i < NN) ? deg[i] : 0;
    // inclusive wave prefix sum of d
    int p = d;
#pragma unroll
    for (int off = 1; off < 64; off <<= 1) {
        int v = __shfl_up(p, off, 64);
        if (lane >= off) p += v;
    }
    int total = __shfl(p, 63, 64);
    int base = 0;
    if (lane == 63) base = atomicAdd(gcount, total);
    base = __shfl(base, 63, 64);
    if (i < NN) {
        rowptr[i] = base + p - d;      // exclusive start of this node's range
        rdeg[i]   = (d > 0) ? rsqrtf((float)d) : 0.f;
    }
}

// ------------------------- z = rdeg[r] * (x @ W^T)[r] -----------------------
// 64-row tile per block, 256 threads as 16x16, each thread a 4x4 register tile.
// Xl row-major over k; Wt transposed [k][o] so both LDS read patterns are
// broadcast / 2-way (free). float4 LDS reads -> ~8 ds_read_b128 per 64 FMA.
__global__ __launch_bounds__(256) void k_gemm(const float* __restrict__ x,
                                              const float* __restrict__ W,
                                              const float* __restrict__ rdeg,
                                              float* __restrict__ z, int n) {
    __shared__ float Xl[64][68];
    __shared__ float Wt[64][68];   // Wt[k][o]

    // load + transpose W (one-time, 16 scalar writes/thread)
    for (int i = threadIdx.x; i < FDIM * FDIM; i += 256) {
        int o = i >> 6, k = i & 63;
        Wt[k][o] = W[i];
    }
    // load X tile as float4
    int tile = blockIdx.x * 64;
    for (int i = threadIdx.x; i < 64 * 16; i += 256) {
        int r = i >> 4, c4 = i & 15;
        int gr = tile + r;
        float4 v = (gr < n) ? ((const float4*)x)[gr * 16 + c4]
                            : make_float4(0.f, 0.f, 0.f, 0.f);
        *(float4*)&Xl[r][c4 * 4] = v;
    }
    __syncthreads();

    int tr = threadIdx.x >> 4;   // 0..15 -> rows tr*4 .. tr*4+3
    int tc = threadIdx.x & 15;   // 0..15 -> outs tc*4 .. tc*4+3

    float acc[4][4] = {};
#pragma unroll
    for (int k4 = 0; k4 < 16; ++k4) {
        float4 a[4], b[4];
#pragma unroll
        for (int i = 0; i < 4; ++i)
            a[i] = *(const float4*)&Xl[tr * 4 + i][k4 * 4];
#pragma unroll
        for (int kk = 0; kk < 4; ++kk)
            b[kk] = *(const float4*)&Wt[k4 * 4 + kk][tc * 4];
#pragma unroll
        for (int i = 0; i < 4; ++i) {
            acc[i][0] += a[i].x * b[0].x + a[i].y * b[1].x + a[i].z * b[2].x + a[i].w * b[3].x;
            acc[i][1] += a[i].x * b[0].y + a[i].y * b[1].y + a[i].z * b[2].y + a[i].w * b[3].y;
            acc[i][2] += a[i].x * b[0].z + a[i].y * b[1].z + a[i].z * b[2].z + a[i].w * b[3].z;
            acc[i][3] += a[i].x * b[0].w + a[i].y * b[1].w + a[i].z * b[2].w + a[i].w * b[3].w;
        }
    }

#pragma unroll
    for (int i = 0; i < 4; ++i) {
        int gr = tile + tr * 4 + i;
        if (gr < n) {
            float s = rdeg[gr];
            float4 v = make_float4(s * acc[i][0], s * acc[i][1],
                                   s * acc[i][2], s * acc[i][3]);
            ((float4*)z)[gr * 16 + tc] = v;
        }
    }
}

// ------------------------------- bucket-fill CSR ----------------------------
__global__ void k_bucket(const int* __restrict__ rowi, const int* __restrict__ coli,
                         const int* __restrict__ rowptr, int* __restrict__ cursor,
                         int* __restrict__ erow, int E) {
    int i = blockIdx.x * blockDim.x + threadIdx.x;
    int stride = gridDim.x * blockDim.x;
    for (; i < E; i += stride) {
        int c = coli[i];
        int p = atomicAdd(&cursor[c], 1);
        erow[rowptr[c] + p] = rowi[i];
    }
}

// --------------------- gather: out[c] = rdeg[c]*sum z[r] + b ----------------
__global__ void k_gather(const int* __restrict__ rowptr, const int* __restrict__ deg,
                         const int* __restrict__ erow,
                         const float* __restrict__ z, const float* __restrict__ rdeg,
                         const float* __restrict__ b, float* __restrict__ out) {
    int lane = threadIdx.x & 63;
    int node = (int)((blockIdx.x * blockDim.x + threadIdx.x) >> 6);
    if (node >= NN) return;
    int s = rowptr[node];
    int e = s + deg[node];
    float acc = 0.f;
    for (int base = s; base < e; base += 64) {
        int cnt = min(64, e - base);
        int idx = (lane < cnt) ? erow[base + lane] : 0;
        for (int j = 0; j < cnt; ++j) {
            int r = __shfl(idx, j, 64);
            acc += z[r * FDIM + lane];
        }
    }
    out[node * FDIM + lane] = rdeg[node] * acc + b[lane];
}

// ---------------------------------------------------------------------------
extern "C" void kernel_launch(void* const* d_in, const int* in_sizes, int n_in,
                              void* d_out, int out_size, void* d_ws, size_t ws_size,
                              hipStream_t stream) {
    const float* x   = (const float*)d_in[0];
    // d_in[1] = x0 (unused: use_init=False)
    const int*   ei  = (const int*)d_in[2];   // harness stores integers as int32
    const float* W_w = (const float*)d_in[3];
    const float* W_b = (const float*)d_in[4];
    float*       out = (float*)d_out;

    const int* rowi = ei;        // edge_index[0]
    const int* coli = ei + NE;   // edge_index[1]

    // workspace layout (256B-aligned chunks):
    char* p = (char*)d_ws;
    auto alloc = [&](size_t bytes) {
        char* r = p;
        p += (bytes + 255) & ~(size_t)255;
        return r;
    };
    // zero-block: deg | cursor | gcount  (single memset)
    int*   deg    = (int*)alloc(NN * sizeof(int));
    int*   cursor = (int*)alloc(NN * sizeof(int));
    int*   gcount = (int*)alloc(256);
    int*   rowptr = (int*)alloc(NN * sizeof(int));
    float* rdeg   = (float*)alloc(NN * sizeof(float));
    int*   erow   = (int*)alloc((size_t)NE * sizeof(int));
    float* z      = (float*)alloc((size_t)NN * FDIM * sizeof(float));

    size_t zero_bytes = (char*)(gcount) + 256 - (char*)deg;
    hipMemsetAsync(deg, 0, zero_bytes, stream);

    k_degree <<<2048, 256, 0, stream>>>(coli, deg, NE);
    k_offsets<<<(NN + 255) / 256, 256, 0, stream>>>(deg, rowptr, rdeg, gcount);
    k_gemm   <<<(NN + 63) / 64, 256, 0, stream>>>(x, W_w, rdeg, z, NN);
    k_bucket <<<2048, 256, 0, stream>>>(rowi, coli, rowptr, cursor, erow, NE);
    k_gather <<<(NN + 3) / 4, 256, 0, stream>>>(rowptr, deg, erow, z, rdeg, W_b, out);
}

// Round 5
// 173.447 us; speedup vs baseline: 1.8182x; 1.1234x over previous
//
#include <hip/hip_runtime.h>

#define NN 50000
#define NE 800000
#define FDIM 64

__device__ __forceinline__ unsigned rne_bf16(float f) {
    unsigned u = __float_as_uint(f);
    return (u + 0x7fffu + ((u >> 16) & 1u)) >> 16;
}

// ---------------------------------------------------------------- degree ----
__global__ void k_degree(const int4* __restrict__ col4, int* __restrict__ deg, int E4) {
    int i = blockIdx.x * blockDim.x + threadIdx.x;
    int stride = gridDim.x * blockDim.x;
    for (; i < E4; i += stride) {
        int4 c = col4[i];
        atomicAdd(&deg[c.x], 1); atomicAdd(&deg[c.y], 1);
        atomicAdd(&deg[c.z], 1); atomicAdd(&deg[c.w], 1);
    }
}

// ---- CSR range reservation; cursor = rowptr copy; rdeg = rsqrt(deg) --------
__global__ void k_offsets(const int* __restrict__ deg, int* __restrict__ rowptr,
                          int* __restrict__ cursor, float* __restrict__ rdeg,
                          int* __restrict__ gcount) {
    int i = blockIdx.x * blockDim.x + threadIdx.x;
    int lane = threadIdx.x & 63;
    int d = (i < NN) ? deg[i] : 0;
    int p = d;
#pragma unroll
    for (int off = 1; off < 64; off <<= 1) {
        int v = __shfl_up(p, off, 64);
        if (lane >= off) p += v;
    }
    int total = __shfl(p, 63, 64);
    int base = 0;
    if (lane == 63) base = atomicAdd(gcount, total);
    base = __shfl(base, 63, 64);
    if (i < NN) {
        int s = base + p - d;
        rowptr[i] = s;
        cursor[i] = s;
        rdeg[i]   = (d > 0) ? rsqrtf((float)d) : 0.f;
    }
}

// --------------- z(bf16) = rdeg[r] * (x @ W^T)[r] ---------------------------
__global__ __launch_bounds__(256) void k_gemm(const float* __restrict__ x,
                                              const float* __restrict__ W,
                                              const float* __restrict__ rdeg,
                                              unsigned* __restrict__ z, int n) {
    __shared__ float Xl[64][68];
    __shared__ float Wt[64][68];   // Wt[k][o]

    for (int i = threadIdx.x; i < FDIM * FDIM; i += 256) {
        int o = i >> 6, k = i & 63;
        Wt[k][o] = W[i];
    }
    int tile = blockIdx.x * 64;
    for (int i = threadIdx.x; i < 64 * 16; i += 256) {
        int r = i >> 4, c4 = i & 15;
        int gr = tile + r;
        float4 v = (gr < n) ? ((const float4*)x)[gr * 16 + c4]
                            : make_float4(0.f, 0.f, 0.f, 0.f);
        *(float4*)&Xl[r][c4 * 4] = v;
    }
    __syncthreads();

    int tr = threadIdx.x >> 4;
    int tc = threadIdx.x & 15;

    float acc[4][4] = {};
#pragma unroll
    for (int k4 = 0; k4 < 16; ++k4) {
        float4 a[4], b[4];
#pragma unroll
        for (int i = 0; i < 4; ++i)
            a[i] = *(const float4*)&Xl[tr * 4 + i][k4 * 4];
#pragma unroll
        for (int kk = 0; kk < 4; ++kk)
            b[kk] = *(const float4*)&Wt[k4 * 4 + kk][tc * 4];
#pragma unroll
        for (int i = 0; i < 4; ++i) {
            acc[i][0] += a[i].x * b[0].x + a[i].y * b[1].x + a[i].z * b[2].x + a[i].w * b[3].x;
            acc[i][1] += a[i].x * b[0].y + a[i].y * b[1].y + a[i].z * b[2].y + a[i].w * b[3].y;
            acc[i][2] += a[i].x * b[0].z + a[i].y * b[1].z + a[i].z * b[2].z + a[i].w * b[3].z;
            acc[i][3] += a[i].x * b[0].w + a[i].y * b[1].w + a[i].z * b[2].w + a[i].w * b[3].w;
        }
    }

#pragma unroll
    for (int i = 0; i < 4; ++i) {
        int gr = tile + tr * 4 + i;
        if (gr < n) {
            float s = rdeg[gr];
            unsigned u01 = rne_bf16(s * acc[i][0]) | (rne_bf16(s * acc[i][1]) << 16);
            unsigned u23 = rne_bf16(s * acc[i][2]) | (rne_bf16(s * acc[i][3]) << 16);
            ((uint2*)z)[gr * 16 + tc] = make_uint2(u01, u23);
        }
    }
}

// ------------------------------- bucket-fill CSR ----------------------------
__global__ void k_bucket(const int4* __restrict__ row4, const int4* __restrict__ col4,
                         int* __restrict__ cursor, unsigned short* __restrict__ erow,
                         int E4) {
    int i = blockIdx.x * blockDim.x + threadIdx.x;
    int stride = gridDim.x * blockDim.x;
    for (; i < E4; i += stride) {
        int4 r = row4[i];
        int4 c = col4[i];
        erow[atomicAdd(&cursor[c.x], 1)] = (unsigned short)r.x;
        erow[atomicAdd(&cursor[c.y], 1)] = (unsigned short)r.y;
        erow[atomicAdd(&cursor[c.z], 1)] = (unsigned short)r.z;
        erow[atomicAdd(&cursor[c.w], 1)] = (unsigned short)r.w;
    }
}

// ------- gather: wave per node, 2 edges/iter (bf16x2 lanes), halves combine -
__global__ __launch_bounds__(256) void k_gather(
        const int* __restrict__ rowptr, const int* __restrict__ deg,
        const unsigned short* __restrict__ erow, const unsigned* __restrict__ z2,
        const float* __restrict__ rdeg, const float* __restrict__ b,
        float* __restrict__ out) {
    int lane = threadIdx.x & 63;
    int node = (int)((blockIdx.x * blockDim.x + threadIdx.x) >> 6);
    if (node >= NN) return;
    int s = rowptr[node];
    int d = deg[node];
    int half = lane >> 5;     // which edge of a pair
    int sl   = lane & 31;     // feature-pair index (features 2sl, 2sl+1)
    float ax = 0.f, ay = 0.f;
    for (int base = 0; base < d; base += 64) {
        int cnt = min(64, d - base);
        int idx = (lane < cnt) ? (int)erow[s + base + lane] : 0;
        int jcnt = (cnt + 1) >> 1;
#pragma unroll 4
        for (int j = 0; j < jcnt; ++j) {
            int ei = 2 * j + half;
            int r  = __shfl(idx, ei, 64);
            unsigned u = z2[r * 32 + sl];
            float lo = __uint_as_float(u << 16);
            float hi = __uint_as_float(u & 0xffff0000u);
            bool ok = ei < cnt;
            ax += ok ? lo : 0.f;
            ay += ok ? hi : 0.f;
        }
    }
    ax += __shfl_xor(ax, 32, 64);
    ay += __shfl_xor(ay, 32, 64);
    if (half == 0) {
        float sc = rdeg[node];
        float2 bb = ((const float2*)b)[sl];
        ((float2*)out)[node * 32 + sl] = make_float2(sc * ax + bb.x, sc * ay + bb.y);
    }
}

// ---------------------------------------------------------------------------
extern "C" void kernel_launch(void* const* d_in, const int* in_sizes, int n_in,
                              void* d_out, int out_size, void* d_ws, size_t ws_size,
                              hipStream_t stream) {
    const float* x   = (const float*)d_in[0];
    // d_in[1] = x0 (unused: use_init=False)
    const int*   ei  = (const int*)d_in[2];   // harness stores integers as int32
    const float* W_w = (const float*)d_in[3];
    const float* W_b = (const float*)d_in[4];
    float*       out = (float*)d_out;

    const int4* row4 = (const int4*)ei;          // edge_index[0]
    const int4* col4 = (const int4*)(ei + NE);   // edge_index[1]
    const int E4 = NE / 4;

    char* p = (char*)d_ws;
    auto alloc = [&](size_t bytes) {
        char* r = p;
        p += (bytes + 255) & ~(size_t)255;
        return r;
    };
    // zero-block: deg | gcount (single memset)
    int*            deg    = (int*)alloc(NN * sizeof(int));
    int*            gcount = (int*)alloc(256);
    int*            cursor = (int*)alloc(NN * sizeof(int));
    int*            rowptr = (int*)alloc(NN * sizeof(int));
    float*          rdeg   = (float*)alloc(NN * sizeof(float));
    unsigned short* erow   = (unsigned short*)alloc((size_t)NE * sizeof(unsigned short));
    unsigned*       z      = (unsigned*)alloc((size_t)NN * 32 * sizeof(unsigned));

    size_t zero_bytes = ((char*)gcount + 256) - (char*)deg;
    hipMemsetAsync(deg, 0, zero_bytes, stream);

    k_degree <<<1024, 256, 0, stream>>>(col4, deg, E4);
    k_offsets<<<(NN + 255) / 256, 256, 0, stream>>>(deg, rowptr, cursor, rdeg, gcount);
    k_gemm   <<<(NN + 63) / 64, 256, 0, stream>>>(x, W_w, rdeg, z, NN);
    k_bucket <<<1024, 256, 0, stream>>>(row4, col4, cursor, erow, E4);
    k_gather <<<(NN + 3) / 4, 256, 0, stream>>>(rowptr, deg, erow, z, rdeg, W_b, out);
}

// Round 6
// 114.441 us; speedup vs baseline: 2.7557x; 1.5156x over previous
//
#include <hip/hip_runtime.h>

#define NN 50000
#define NE 800000
#define FDIM 64
#define NB 8          // coarse buckets == XCDs
#define P1B 192       // pass-1 blocks (block-private regions)
#define RCAP 1024     // per (bucket, block) region capacity
#define CAP 64        // per-node erow slots (max degree ~45 for Poisson(16))
#define OVFCAP 16384
#define NPX 6250      // nodes per XCD range (50000/8)

__device__ __forceinline__ unsigned rne_bf16(float f) {
    unsigned u = __float_as_uint(f);
    return (u + 0x7fffu + ((u >> 16) & 1u)) >> 16;
}

// ---- pass 1: partition edges into 8 dest-range buckets, block-private ------
__global__ __launch_bounds__(256) void k_part(const int* __restrict__ rowi,
                                              const int* __restrict__ coli,
                                              unsigned* __restrict__ buckets,
                                              int* __restrict__ bcnt,
                                              unsigned* __restrict__ ovf,
                                              int* __restrict__ ovfcnt) {
    __shared__ int lcnt[NB];
    if (threadIdx.x < NB) lcnt[threadIdx.x] = 0;
    __syncthreads();
    int stride = gridDim.x * blockDim.x;
    for (int i = blockIdx.x * blockDim.x + threadIdx.x; i < NE; i += stride) {
        int r = rowi[i], c = coli[i];
        int b = min(NB - 1, (int)((float)c * (8.0f / 50000.0f)));
        unsigned pk = ((unsigned)r << 16) | (unsigned)c;
        int slot = atomicAdd(&lcnt[b], 1);                 // LDS atomic
        if (slot < RCAP)
            buckets[(size_t)(b * P1B + blockIdx.x) * RCAP + slot] = pk;
        else {                                             // impossible (+23 sigma), guarded
            int o = atomicAdd(ovfcnt, 1);
            if (o < OVFCAP) ovf[o] = pk;
        }
    }
    __syncthreads();
    if (threadIdx.x < NB)
        bcnt[threadIdx.x * P1B + blockIdx.x] = min(lcnt[threadIdx.x], RCAP);
}

// ---- pass 2: XCD-local degree count + fixed-capacity erow fill -------------
__global__ __launch_bounds__(256) void k_fill(const unsigned* __restrict__ buckets,
                                              const int* __restrict__ bcnt,
                                              int* __restrict__ cnt,
                                              unsigned short* __restrict__ erow,
                                              unsigned* __restrict__ ovf,
                                              int* __restrict__ ovfcnt) {
    int k  = blockIdx.x & (NB - 1);    // bucket == (assumed) XCD of this block
    int b1 = blockIdx.x >> 3;
    int m  = bcnt[k * P1B + b1];
    const unsigned* reg = buckets + (size_t)(k * P1B + b1) * RCAP;
    for (int i = threadIdx.x; i < m; i += 256) {
        unsigned pk = reg[i];
        int c = (int)(pk & 0xffffu), r = (int)(pk >> 16);
        int p = atomicAdd(&cnt[c], 1);                     // doubles as degree count
        if (p < CAP) erow[c * CAP + p] = (unsigned short)r;
        else {                                             // deg > 64: impossible, guarded
            int o = atomicAdd(ovfcnt, 1);
            if (o < OVFCAP) ovf[o] = pk;
        }
    }
}

// ---- z(bf16) = rsqrt(deg[r]) * (x @ W^T)[r] --------------------------------
__global__ __launch_bounds__(256) void k_gemm(const float* __restrict__ x,
                                              const float* __restrict__ W,
                                              const int* __restrict__ cnt,
                                              unsigned* __restrict__ z, int n) {
    __shared__ float Xl[64][68];
    __shared__ float Wt[64][68];   // Wt[k][o]

    for (int i = threadIdx.x; i < FDIM * FDIM; i += 256) {
        int o = i >> 6, k = i & 63;
        Wt[k][o] = W[i];
    }
    int tile = blockIdx.x * 64;
    for (int i = threadIdx.x; i < 64 * 16; i += 256) {
        int r = i >> 4, c4 = i & 15;
        int gr = tile + r;
        float4 v = (gr < n) ? ((const float4*)x)[gr * 16 + c4]
                            : make_float4(0.f, 0.f, 0.f, 0.f);
        *(float4*)&Xl[r][c4 * 4] = v;
    }
    __syncthreads();

    int tr = threadIdx.x >> 4;
    int tc = threadIdx.x & 15;

    float acc[4][4] = {};
#pragma unroll
    for (int k4 = 0; k4 < 16; ++k4) {
        float4 a[4], b[4];
#pragma unroll
        for (int i = 0; i < 4; ++i)
            a[i] = *(const float4*)&Xl[tr * 4 + i][k4 * 4];
#pragma unroll
        for (int kk = 0; kk < 4; ++kk)
            b[kk] = *(const float4*)&Wt[k4 * 4 + kk][tc * 4];
#pragma unroll
        for (int i = 0; i < 4; ++i) {
            acc[i][0] += a[i].x * b[0].x + a[i].y * b[1].x + a[i].z * b[2].x + a[i].w * b[3].x;
            acc[i][1] += a[i].x * b[0].y + a[i].y * b[1].y + a[i].z * b[2].y + a[i].w * b[3].y;
            acc[i][2] += a[i].x * b[0].z + a[i].y * b[1].z + a[i].z * b[2].z + a[i].w * b[3].z;
            acc[i][3] += a[i].x * b[0].w + a[i].y * b[1].w + a[i].z * b[2].w + a[i].w * b[3].w;
        }
    }

#pragma unroll
    for (int i = 0; i < 4; ++i) {
        int gr = tile + tr * 4 + i;
        if (gr < n) {
            int dc = cnt[gr];
            float s = (dc > 0) ? rsqrtf((float)dc) : 0.f;
            unsigned u01 = rne_bf16(s * acc[i][0]) | (rne_bf16(s * acc[i][1]) << 16);
            unsigned u23 = rne_bf16(s * acc[i][2]) | (rne_bf16(s * acc[i][3]) << 16);
            ((uint2*)z)[gr * 16 + tc] = make_uint2(u01, u23);
        }
    }
}

// ---- gather: wave/node, 8 edges per iter, 8 lanes per edge (uint4 = row) ---
__global__ __launch_bounds__(256) void k_gather(
        const int* __restrict__ cnt, const unsigned short* __restrict__ erow,
        const uint4* __restrict__ z4, const float* __restrict__ bias,
        float* __restrict__ out) {
    int lane = threadIdx.x & 63;
    int wv   = threadIdx.x >> 6;
    int xk   = blockIdx.x & 7;          // node range == (assumed) XCD
    int sub  = blockIdx.x >> 3;
    int loc  = sub * 4 + wv;
    if (loc >= NPX) return;
    int node = xk * NPX + loc;

    int d  = cnt[node];
    int dc = min(d, CAP);
    int grp = lane >> 3, sl = lane & 7;
    int idx = (int)erow[node * CAP + lane];   // slots >= dc are garbage, masked below

    float a0=0,a1=0,a2=0,a3=0,a4=0,a5=0,a6=0,a7=0;
    int octets = (dc + 7) >> 3;
    for (int j = 0; j < octets; ++j) {
        int ei = j * 8 + grp;
        int rr = __shfl(idx, ei, 64);
        bool ok = ei < dc;
        rr = ok ? rr : 0;                      // keep load in-bounds
        uint4 u = z4[rr * 8 + sl];
        if (!ok) { u.x = 0; u.y = 0; u.z = 0; u.w = 0; }
        a0 += __uint_as_float(u.x << 16);
        a1 += __uint_as_float(u.x & 0xffff0000u);
        a2 += __uint_as_float(u.y << 16);
        a3 += __uint_as_float(u.y & 0xffff0000u);
        a4 += __uint_as_float(u.z << 16);
        a5 += __uint_as_float(u.z & 0xffff0000u);
        a6 += __uint_as_float(u.w << 16);
        a7 += __uint_as_float(u.w & 0xffff0000u);
    }
#pragma unroll
    for (int m = 8; m <= 32; m <<= 1) {
        a0 += __shfl_xor(a0, m, 64); a1 += __shfl_xor(a1, m, 64);
        a2 += __shfl_xor(a2, m, 64); a3 += __shfl_xor(a3, m, 64);
        a4 += __shfl_xor(a4, m, 64); a5 += __shfl_xor(a5, m, 64);
        a6 += __shfl_xor(a6, m, 64); a7 += __shfl_xor(a7, m, 64);
    }
    if (grp == 0) {
        float sc = (d > 0) ? rsqrtf((float)d) : 0.f;
        float4 b0 = ((const float4*)bias)[sl * 2];
        float4 b1 = ((const float4*)bias)[sl * 2 + 1];
        float4 o0 = make_float4(sc*a0+b0.x, sc*a1+b0.y, sc*a2+b0.z, sc*a3+b0.w);
        float4 o1 = make_float4(sc*a4+b1.x, sc*a5+b1.y, sc*a6+b1.z, sc*a7+b1.w);
        ((float4*)out)[node * 16 + sl * 2]     = o0;
        ((float4*)out)[node * 16 + sl * 2 + 1] = o1;
    }
}

// ---- overflow fixup (expected 0 entries; pure safety) ----------------------
__global__ void k_fixup(const unsigned* __restrict__ ovf, const int* __restrict__ ovfcnt,
                        const int* __restrict__ cnt, const unsigned* __restrict__ z2,
                        float* __restrict__ out) {
    int lane = threadIdx.x & 63;
    int wv   = threadIdx.x >> 6;
    int n = min(*ovfcnt, OVFCAP);
    for (int i = wv; i < n; i += 4) {
        unsigned pk = ovf[i];
        int c = (int)(pk & 0xffffu), r = (int)(pk >> 16);
        float sc = rsqrtf((float)max(cnt[c], 1));
        unsigned u = z2[r * 32 + (lane >> 1)];
        float v = (lane & 1) ? __uint_as_float(u & 0xffff0000u)
                             : __uint_as_float(u << 16);
        atomicAdd(&out[c * 64 + lane], sc * v);
    }
}

// ---------------------------------------------------------------------------
extern "C" void kernel_launch(void* const* d_in, const int* in_sizes, int n_in,
                              void* d_out, int out_size, void* d_ws, size_t ws_size,
                              hipStream_t stream) {
    const float* x   = (const float*)d_in[0];
    // d_in[1] = x0 (unused: use_init=False)
    const int*   ei  = (const int*)d_in[2];   // harness stores integers as int32
    const float* W_w = (const float*)d_in[3];
    const float* W_b = (const float*)d_in[4];
    float*       out = (float*)d_out;

    const int* rowi = ei;        // edge_index[0]
    const int* coli = ei + NE;   // edge_index[1]

    char* p = (char*)d_ws;
    auto alloc = [&](size_t bytes) {
        char* r = p;
        p += (bytes + 255) & ~(size_t)255;
        return r;
    };
    // zero-block: cnt | ovfcnt (single memset)
    int*            cnt    = (int*)alloc(NN * sizeof(int));
    int*            ovfcnt = (int*)alloc(256);
    unsigned*       ovf    = (unsigned*)alloc(OVFCAP * sizeof(unsigned));
    int*            bcnt   = (int*)alloc(NB * P1B * sizeof(int));
    unsigned short* erow   = (unsigned short*)alloc((size_t)NN * CAP * sizeof(unsigned short));
    // overlay: buckets (pass1/pass2 only) and z (gemm onward) share memory
    size_t buckets_bytes = (size_t)NB * P1B * RCAP * sizeof(unsigned);   // 6.0 MB
    size_t z_bytes       = (size_t)NN * FDIM * 2;                        // 6.4 MB
    char* overlay = alloc(buckets_bytes > z_bytes ? buckets_bytes : z_bytes);
    unsigned* buckets = (unsigned*)overlay;
    unsigned* z       = (unsigned*)overlay;

    size_t zero_bytes = ((char*)ovfcnt + 256) - (char*)cnt;
    hipMemsetAsync(cnt, 0, zero_bytes, stream);

    k_part  <<<P1B, 256, 0, stream>>>(rowi, coli, buckets, bcnt, ovf, ovfcnt);
    k_fill  <<<NB * P1B, 256, 0, stream>>>(buckets, bcnt, cnt, erow, ovf, ovfcnt);
    k_gemm  <<<(NN + 63) / 64, 256, 0, stream>>>(x, W_w, cnt, z, NN);
    k_gather<<<NB * ((NPX + 3) / 4), 256, 0, stream>>>(cnt, erow, (const uint4*)z, W_b, out);
    k_fixup <<<1, 256, 0, stream>>>(ovf, ovfcnt, cnt, z, out);
}

// Round 8
// 111.228 us; speedup vs baseline: 2.8353x; 1.0289x over previous
//
#include <hip/hip_runtime.h>

#define NN 50000
#define NE 800000
#define FDIM 64
#define NB 8          // coarse buckets == XCDs
#define P1B 192       // pass-1 blocks (block-private regions)
#define RCAP 1024     // per (bucket, block) region capacity
#define CAP 64        // per-node erow slots (max degree ~45 for Poisson(16))
#define OVFCAP 16384
#define NPX 6250      // nodes per XCD range (50000/8)

typedef float f32x4 __attribute__((ext_vector_type(4)));

__device__ __forceinline__ unsigned rne_bf16(float f) {
    unsigned u = __float_as_uint(f);
    return (u + 0x7fffu + ((u >> 16) & 1u)) >> 16;
}

// ---- pass 1: partition edges into 8 dest-range buckets, block-private ------
__global__ __launch_bounds__(256) void k_part(const int4* __restrict__ row4,
                                              const int4* __restrict__ col4,
                                              unsigned* __restrict__ buckets,
                                              int* __restrict__ bcnt,
                                              unsigned* __restrict__ ovf,
                                              int* __restrict__ ovfcnt) {
    __shared__ int lcnt[NB];
    if (threadIdx.x < NB) lcnt[threadIdx.x] = 0;
    __syncthreads();
    const int E4 = NE / 4;
    int stride = gridDim.x * blockDim.x;
    for (int i = blockIdx.x * blockDim.x + threadIdx.x; i < E4; i += stride) {
        int4 r4 = row4[i];
        int4 c4 = col4[i];
        int rr[4] = {r4.x, r4.y, r4.z, r4.w};
        int cc[4] = {c4.x, c4.y, c4.z, c4.w};
#pragma unroll
        for (int t = 0; t < 4; ++t) {
            int c = cc[t];
            int b = (int)(((unsigned long long)(unsigned)c * 687195ull) >> 32); // c/6250
            unsigned pk = ((unsigned)rr[t] << 16) | (unsigned)c;
            int slot = atomicAdd(&lcnt[b], 1);             // LDS atomic
            if (slot < RCAP)
                buckets[(size_t)(b * P1B + blockIdx.x) * RCAP + slot] = pk;
            else {                                         // impossible, guarded
                int o = atomicAdd(ovfcnt, 1);
                if (o < OVFCAP) ovf[o] = pk;
            }
        }
    }
    __syncthreads();
    if (threadIdx.x < NB)
        bcnt[threadIdx.x * P1B + blockIdx.x] = min(lcnt[threadIdx.x], RCAP);
}

// ---- pass 2: XCD-local degree count + fixed-capacity erow fill -------------
__global__ __launch_bounds__(256) void k_fill(const unsigned* __restrict__ buckets,
                                              const int* __restrict__ bcnt,
                                              int* __restrict__ cnt,
                                              unsigned short* __restrict__ erow,
                                              unsigned* __restrict__ ovf,
                                              int* __restrict__ ovfcnt) {
    int k  = blockIdx.x & (NB - 1);    // bucket == (assumed) XCD of this block
    int b1 = blockIdx.x >> 3;
    int m  = bcnt[k * P1B + b1];
    const unsigned* reg = buckets + (size_t)(k * P1B + b1) * RCAP;
    for (int i = threadIdx.x; i < m; i += 256) {
        unsigned pk = reg[i];
        int c = (int)(pk & 0xffffu), r = (int)(pk >> 16);
        int p = atomicAdd(&cnt[c], 1);                     // doubles as degree count
        if (p < CAP) erow[c * CAP + p] = (unsigned short)r;
        else {                                             // deg > 64: impossible, guarded
            int o = atomicAdd(ovfcnt, 1);
            if (o < OVFCAP) ovf[o] = pk;
        }
    }
}

// ---- z(bf16) = rsqrt(deg[r]) * (x @ W^T)[r] --------------------------------
__global__ __launch_bounds__(256) void k_gemm(const float* __restrict__ x,
                                              const float* __restrict__ W,
                                              const int* __restrict__ cnt,
                                              unsigned* __restrict__ z, int n) {
    __shared__ float Xl[64][68];
    __shared__ float Wt[64][68];   // Wt[k][o]

    for (int i = threadIdx.x; i < FDIM * FDIM; i += 256) {
        int o = i >> 6, k = i & 63;
        Wt[k][o] = W[i];
    }
    int tile = blockIdx.x * 64;
    for (int i = threadIdx.x; i < 64 * 16; i += 256) {
        int r = i >> 4, c4 = i & 15;
        int gr = tile + r;
        f32x4 v = (gr < n) ? __builtin_nontemporal_load(&((const f32x4*)x)[gr * 16 + c4])
                           : (f32x4){0.f, 0.f, 0.f, 0.f};
        *(f32x4*)&Xl[r][c4 * 4] = v;
    }
    __syncthreads();

    int tr = threadIdx.x >> 4;
    int tc = threadIdx.x & 15;

    float acc[4][4] = {};
#pragma unroll
    for (int k4 = 0; k4 < 16; ++k4) {
        f32x4 a[4], b[4];
#pragma unroll
        for (int i = 0; i < 4; ++i)
            a[i] = *(const f32x4*)&Xl[tr * 4 + i][k4 * 4];
#pragma unroll
        for (int kk = 0; kk < 4; ++kk)
            b[kk] = *(const f32x4*)&Wt[k4 * 4 + kk][tc * 4];
#pragma unroll
        for (int i = 0; i < 4; ++i) {
#pragma unroll
            for (int jj = 0; jj < 4; ++jj) {
                acc[i][jj] += a[i].x * b[0][jj] + a[i].y * b[1][jj]
                            + a[i].z * b[2][jj] + a[i].w * b[3][jj];
            }
        }
    }

#pragma unroll
    for (int i = 0; i < 4; ++i) {
        int gr = tile + tr * 4 + i;
        if (gr < n) {
            int dc = cnt[gr];
            float s = (dc > 0) ? rsqrtf((float)dc) : 0.f;
            unsigned u01 = rne_bf16(s * acc[i][0]) | (rne_bf16(s * acc[i][1]) << 16);
            unsigned u23 = rne_bf16(s * acc[i][2]) | (rne_bf16(s * acc[i][3]) << 16);
            ((uint2*)z)[gr * 16 + tc] = make_uint2(u01, u23);
        }
    }
}

// ---- gather: wave/node, 8 edges per iter, 8 lanes per edge (uint4 = row) ---
// inline overflow drain (ovfcnt==0 in practice); nontemporal out stores
__global__ __launch_bounds__(256) void k_gather(
        const int* __restrict__ cnt, const unsigned short* __restrict__ erow,
        const uint4* __restrict__ z4, const float* __restrict__ bias,
        const unsigned* __restrict__ ovf, const int* __restrict__ ovfcnt,
        float* __restrict__ out) {
    int lane = threadIdx.x & 63;
    int wv   = threadIdx.x >> 6;
    int xk   = blockIdx.x & 7;          // node range == (assumed) XCD
    int sub  = blockIdx.x >> 3;
    int loc  = sub * 4 + wv;
    if (loc >= NPX) return;
    int node = xk * NPX + loc;

    int d  = cnt[node];
    int dc = min(d, CAP);
    int grp = lane >> 3, sl = lane & 7;
    int idx = (int)erow[node * CAP + lane];   // slots >= dc are garbage, masked below

    float a0=0,a1=0,a2=0,a3=0,a4=0,a5=0,a6=0,a7=0;
    int octets = (dc + 7) >> 3;
    for (int j = 0; j < octets; ++j) {
        int ei = j * 8 + grp;
        int rr = __shfl(idx, ei, 64);          // uniform control flow for shfl
        if (ei < dc) {                          // exec-masked: suppresses the load
            uint4 u = z4[rr * 8 + sl];
            a0 += __uint_as_float(u.x << 16);
            a1 += __uint_as_float(u.x & 0xffff0000u);
            a2 += __uint_as_float(u.y << 16);
            a3 += __uint_as_float(u.y & 0xffff0000u);
            a4 += __uint_as_float(u.z << 16);
            a5 += __uint_as_float(u.z & 0xffff0000u);
            a6 += __uint_as_float(u.w << 16);
            a7 += __uint_as_float(u.w & 0xffff0000u);
        }
    }

    // overflow drain (impossible path, kept for strict correctness)
    int ovn = min(*ovfcnt, OVFCAP);
    if (ovn > 0) {
        for (int i = 0; i < ovn; ++i) {
            unsigned pk = ovf[i];
            if ((int)(pk & 0xffffu) == node && grp == 0) {
                uint4 u = z4[(pk >> 16) * 8 + sl];
                a0 += __uint_as_float(u.x << 16);
                a1 += __uint_as_float(u.x & 0xffff0000u);
                a2 += __uint_as_float(u.y << 16);
                a3 += __uint_as_float(u.y & 0xffff0000u);
                a4 += __uint_as_float(u.z << 16);
                a5 += __uint_as_float(u.z & 0xffff0000u);
                a6 += __uint_as_float(u.w << 16);
                a7 += __uint_as_float(u.w & 0xffff0000u);
            }
        }
    }

#pragma unroll
    for (int m = 8; m <= 32; m <<= 1) {
        a0 += __shfl_xor(a0, m, 64); a1 += __shfl_xor(a1, m, 64);
        a2 += __shfl_xor(a2, m, 64); a3 += __shfl_xor(a3, m, 64);
        a4 += __shfl_xor(a4, m, 64); a5 += __shfl_xor(a5, m, 64);
        a6 += __shfl_xor(a6, m, 64); a7 += __shfl_xor(a7, m, 64);
    }
    if (grp == 0) {
        float sc = (d > 0) ? rsqrtf((float)d) : 0.f;
        f32x4 b0 = ((const f32x4*)bias)[sl * 2];
        f32x4 b1 = ((const f32x4*)bias)[sl * 2 + 1];
        f32x4 o0 = {sc*a0+b0.x, sc*a1+b0.y, sc*a2+b0.z, sc*a3+b0.w};
        f32x4 o1 = {sc*a4+b1.x, sc*a5+b1.y, sc*a6+b1.z, sc*a7+b1.w};
        __builtin_nontemporal_store(o0, &((f32x4*)out)[node * 16 + sl * 2]);
        __builtin_nontemporal_store(o1, &((f32x4*)out)[node * 16 + sl * 2 + 1]);
    }
}

// ---------------------------------------------------------------------------
extern "C" void kernel_launch(void* const* d_in, const int* in_sizes, int n_in,
                              void* d_out, int out_size, void* d_ws, size_t ws_size,
                              hipStream_t stream) {
    const float* x   = (const float*)d_in[0];
    // d_in[1] = x0 (unused: use_init=False)
    const int*   ei  = (const int*)d_in[2];   // harness stores integers as int32
    const float* W_w = (const float*)d_in[3];
    const float* W_b = (const float*)d_in[4];
    float*       out = (float*)d_out;

    const int4* row4 = (const int4*)ei;          // edge_index[0]
    const int4* col4 = (const int4*)(ei + NE);   // edge_index[1]

    char* p = (char*)d_ws;
    auto alloc = [&](size_t bytes) {
        char* r = p;
        p += (bytes + 255) & ~(size_t)255;
        return r;
    };
    // zero-block: cnt | ovfcnt (single memset)
    int*            cnt    = (int*)alloc(NN * sizeof(int));
    int*            ovfcnt = (int*)alloc(256);
    unsigned*       ovf    = (unsigned*)alloc(OVFCAP * sizeof(unsigned));
    int*            bcnt   = (int*)alloc(NB * P1B * sizeof(int));
    unsigned short* erow   = (unsigned short*)alloc((size_t)NN * CAP * sizeof(unsigned short));
    // overlay: buckets (pass1/pass2 only) and z (gemm onward) share memory
    size_t buckets_bytes = (size_t)NB * P1B * RCAP * sizeof(unsigned);   // 6.0 MB
    size_t z_bytes       = (size_t)NN * FDIM * 2;                        // 6.4 MB
    char* overlay = alloc(buckets_bytes > z_bytes ? buckets_bytes : z_bytes);
    unsigned* buckets = (unsigned*)overlay;
    unsigned* z       = (unsigned*)overlay;

    size_t zero_bytes = ((char*)ovfcnt + 256) - (char*)cnt;
    (void)hipMemsetAsync(cnt, 0, zero_bytes, stream);

    k_part  <<<P1B, 256, 0, stream>>>(row4, col4, buckets, bcnt, ovf, ovfcnt);
    k_fill  <<<NB * P1B, 256, 0, stream>>>(buckets, bcnt, cnt, erow, ovf, ovfcnt);
    k_gemm  <<<(NN + 63) / 64, 256, 0, stream>>>(x, W_w, cnt, z, NN);
    k_gather<<<NB * ((NPX + 3) / 4), 256, 0, stream>>>(cnt, erow, (const uint4*)z, W_b,
                                                       ovf, ovfcnt, out);
}

// Round 9
// 106.629 us; speedup vs baseline: 2.9575x; 1.0431x over previous
//
#include <hip/hip_runtime.h>

#define NN 50000
#define NE 800000
#define FDIM 64
#define NB 8          // coarse buckets == XCDs
#define P1B 192       // pass-1 blocks (block-private regions)
#define RCAP 1024     // per (bucket, block) region capacity
#define CAP 64        // per-node erow slots (max degree ~45 for Poisson(16))
#define OVFCAP 16384
#define NPX 6250      // nodes per XCD range (50000/8)

typedef float f32x4 __attribute__((ext_vector_type(4)));

__device__ __forceinline__ unsigned rne_bf16(float f) {
    unsigned u = __float_as_uint(f);
    return (u + 0x7fffu + ((u >> 16) & 1u)) >> 16;
}

// ---- pass 1: partition edges into 8 dest-range buckets, block-private ------
// Also zeroes cnt/ovfcnt (replaces a hipMemsetAsync dispatch that cost 43us).
__global__ __launch_bounds__(256) void k_part(const int4* __restrict__ row4,
                                              const int4* __restrict__ col4,
                                              unsigned* __restrict__ buckets,
                                              int* __restrict__ bcnt,
                                              int* __restrict__ cnt,
                                              unsigned* __restrict__ ovf,
                                              int* __restrict__ ovfcnt) {
    // zero cnt (consumed by k_fill, next kernel -> visibility guaranteed)
    int gid = blockIdx.x * blockDim.x + threadIdx.x;
    int gstride = gridDim.x * blockDim.x;
    for (int i = gid; i < NN; i += gstride) cnt[i] = 0;
    if (gid == 0) *ovfcnt = 0;

    __shared__ int lcnt[NB];
    if (threadIdx.x < NB) lcnt[threadIdx.x] = 0;
    __syncthreads();
    const int E4 = NE / 4;
    for (int i = gid; i < E4; i += gstride) {
        int4 r4 = row4[i];
        int4 c4 = col4[i];
        int rr[4] = {r4.x, r4.y, r4.z, r4.w};
        int cc[4] = {c4.x, c4.y, c4.z, c4.w};
#pragma unroll
        for (int t = 0; t < 4; ++t) {
            int c = cc[t];
            int b = (int)(((unsigned long long)(unsigned)c * 687195ull) >> 32); // c/6250
            unsigned pk = ((unsigned)rr[t] << 16) | (unsigned)c;
            int slot = atomicAdd(&lcnt[b], 1);             // LDS atomic
            if (slot < RCAP)
                buckets[(size_t)(b * P1B + blockIdx.x) * RCAP + slot] = pk;
            else {                                         // impossible, guarded
                int o = atomicAdd(ovfcnt, 1);
                if (o < OVFCAP) ovf[o] = pk;
            }
        }
    }
    __syncthreads();
    if (threadIdx.x < NB)
        bcnt[threadIdx.x * P1B + blockIdx.x] = min(lcnt[threadIdx.x], RCAP);
}

// ---- pass 2: XCD-local degree count + fixed-capacity erow fill -------------
__global__ __launch_bounds__(256) void k_fill(const unsigned* __restrict__ buckets,
                                              const int* __restrict__ bcnt,
                                              int* __restrict__ cnt,
                                              unsigned short* __restrict__ erow,
                                              unsigned* __restrict__ ovf,
                                              int* __restrict__ ovfcnt) {
    int k  = blockIdx.x & (NB - 1);    // bucket == (assumed) XCD of this block
    int b1 = blockIdx.x >> 3;
    int m  = bcnt[k * P1B + b1];
    const unsigned* reg = buckets + (size_t)(k * P1B + b1) * RCAP;
    for (int i = threadIdx.x; i < m; i += 256) {
        unsigned pk = reg[i];
        int c = (int)(pk & 0xffffu), r = (int)(pk >> 16);
        int p = atomicAdd(&cnt[c], 1);                     // doubles as degree count
        if (p < CAP) erow[c * CAP + p] = (unsigned short)r;
        else {                                             // deg > 64: impossible, guarded
            int o = atomicAdd(ovfcnt, 1);
            if (o < OVFCAP) ovf[o] = pk;
        }
    }
}

// ---- z(bf16) = rsqrt(deg[r]) * (x @ W^T)[r] --------------------------------
__global__ __launch_bounds__(256) void k_gemm(const float* __restrict__ x,
                                              const float* __restrict__ W,
                                              const int* __restrict__ cnt,
                                              unsigned* __restrict__ z, int n) {
    __shared__ float Xl[64][68];
    __shared__ float Wt[64][68];   // Wt[k][o]

    for (int i = threadIdx.x; i < FDIM * FDIM; i += 256) {
        int o = i >> 6, k = i & 63;
        Wt[k][o] = W[i];
    }
    int tile = blockIdx.x * 64;
    for (int i = threadIdx.x; i < 64 * 16; i += 256) {
        int r = i >> 4, c4 = i & 15;
        int gr = tile + r;
        f32x4 v = (gr < n) ? __builtin_nontemporal_load(&((const f32x4*)x)[gr * 16 + c4])
                           : (f32x4){0.f, 0.f, 0.f, 0.f};
        *(f32x4*)&Xl[r][c4 * 4] = v;
    }
    __syncthreads();

    int tr = threadIdx.x >> 4;
    int tc = threadIdx.x & 15;

    float acc[4][4] = {};
#pragma unroll
    for (int k4 = 0; k4 < 16; ++k4) {
        f32x4 a[4], b[4];
#pragma unroll
        for (int i = 0; i < 4; ++i)
            a[i] = *(const f32x4*)&Xl[tr * 4 + i][k4 * 4];
#pragma unroll
        for (int kk = 0; kk < 4; ++kk)
            b[kk] = *(const f32x4*)&Wt[k4 * 4 + kk][tc * 4];
#pragma unroll
        for (int i = 0; i < 4; ++i) {
#pragma unroll
            for (int jj = 0; jj < 4; ++jj) {
                acc[i][jj] += a[i].x * b[0][jj] + a[i].y * b[1][jj]
                            + a[i].z * b[2][jj] + a[i].w * b[3][jj];
            }
        }
    }

#pragma unroll
    for (int i = 0; i < 4; ++i) {
        int gr = tile + tr * 4 + i;
        if (gr < n) {
            int dc = cnt[gr];
            float s = (dc > 0) ? rsqrtf((float)dc) : 0.f;
            unsigned u01 = rne_bf16(s * acc[i][0]) | (rne_bf16(s * acc[i][1]) << 16);
            unsigned u23 = rne_bf16(s * acc[i][2]) | (rne_bf16(s * acc[i][3]) << 16);
            ((uint2*)z)[gr * 16 + tc] = make_uint2(u01, u23);
        }
    }
}

// ---- gather: wave/node, 8 edges per iter, 8 lanes per edge (uint4 = row) ---
// inline overflow drain (ovfcnt==0 in practice); nontemporal out stores
__global__ __launch_bounds__(256) void k_gather(
        const int* __restrict__ cnt, const unsigned short* __restrict__ erow,
        const uint4* __restrict__ z4, const float* __restrict__ bias,
        const unsigned* __restrict__ ovf, const int* __restrict__ ovfcnt,
        float* __restrict__ out) {
    int lane = threadIdx.x & 63;
    int wv   = threadIdx.x >> 6;
    int xk   = blockIdx.x & 7;          // node range == (assumed) XCD
    int sub  = blockIdx.x >> 3;
    int loc  = sub * 4 + wv;
    if (loc >= NPX) return;
    int node = xk * NPX + loc;

    int d  = cnt[node];
    int dc = min(d, CAP);
    int grp = lane >> 3, sl = lane & 7;
    int idx = (int)erow[node * CAP + lane];   // slots >= dc are garbage, masked below

    float a0=0,a1=0,a2=0,a3=0,a4=0,a5=0,a6=0,a7=0;
    int octets = (dc + 7) >> 3;
    for (int j = 0; j < octets; ++j) {
        int ei = j * 8 + grp;
        int rr = __shfl(idx, ei, 64);          // uniform control flow for shfl
        if (ei < dc) {                          // exec-masked: suppresses the load
            uint4 u = z4[rr * 8 + sl];
            a0 += __uint_as_float(u.x << 16);
            a1 += __uint_as_float(u.x & 0xffff0000u);
            a2 += __uint_as_float(u.y << 16);
            a3 += __uint_as_float(u.y & 0xffff0000u);
            a4 += __uint_as_float(u.z << 16);
            a5 += __uint_as_float(u.z & 0xffff0000u);
            a6 += __uint_as_float(u.w << 16);
            a7 += __uint_as_float(u.w & 0xffff0000u);
        }
    }

    // overflow drain (impossible path, kept for strict correctness)
    int ovn = min(*ovfcnt, OVFCAP);
    if (ovn > 0) {
        for (int i = 0; i < ovn; ++i) {
            unsigned pk = ovf[i];
            if ((int)(pk & 0xffffu) == node && grp == 0) {
                uint4 u = z4[(pk >> 16) * 8 + sl];
                a0 += __uint_as_float(u.x << 16);
                a1 += __uint_as_float(u.x & 0xffff0000u);
                a2 += __uint_as_float(u.y << 16);
                a3 += __uint_as_float(u.y & 0xffff0000u);
                a4 += __uint_as_float(u.z << 16);
                a5 += __uint_as_float(u.z & 0xffff0000u);
                a6 += __uint_as_float(u.w << 16);
                a7 += __uint_as_float(u.w & 0xffff0000u);
            }
        }
    }

#pragma unroll
    for (int m = 8; m <= 32; m <<= 1) {
        a0 += __shfl_xor(a0, m, 64); a1 += __shfl_xor(a1, m, 64);
        a2 += __shfl_xor(a2, m, 64); a3 += __shfl_xor(a3, m, 64);
        a4 += __shfl_xor(a4, m, 64); a5 += __shfl_xor(a5, m, 64);
        a6 += __shfl_xor(a6, m, 64); a7 += __shfl_xor(a7, m, 64);
    }
    if (grp == 0) {
        float sc = (d > 0) ? rsqrtf((float)d) : 0.f;
        f32x4 b0 = ((const f32x4*)bias)[sl * 2];
        f32x4 b1 = ((const f32x4*)bias)[sl * 2 + 1];
        f32x4 o0 = {sc*a0+b0.x, sc*a1+b0.y, sc*a2+b0.z, sc*a3+b0.w};
        f32x4 o1 = {sc*a4+b1.x, sc*a5+b1.y, sc*a6+b1.z, sc*a7+b1.w};
        __builtin_nontemporal_store(o0, &((f32x4*)out)[node * 16 + sl * 2]);
        __builtin_nontemporal_store(o1, &((f32x4*)out)[node * 16 + sl * 2 + 1]);
    }
}

// ---------------------------------------------------------------------------
extern "C" void kernel_launch(void* const* d_in, const int* in_sizes, int n_in,
                              void* d_out, int out_size, void* d_ws, size_t ws_size,
                              hipStream_t stream) {
    const float* x   = (const float*)d_in[0];
    // d_in[1] = x0 (unused: use_init=False)
    const int*   ei  = (const int*)d_in[2];   // harness stores integers as int32
    const float* W_w = (const float*)d_in[3];
    const float* W_b = (const float*)d_in[4];
    float*       out = (float*)d_out;

    const int4* row4 = (const int4*)ei;          // edge_index[0]
    const int4* col4 = (const int4*)(ei + NE);   // edge_index[1]

    char* p = (char*)d_ws;
    auto alloc = [&](size_t bytes) {
        char* r = p;
        p += (bytes + 255) & ~(size_t)255;
        return r;
    };
    int*            cnt    = (int*)alloc(NN * sizeof(int));
    int*            ovfcnt = (int*)alloc(256);
    unsigned*       ovf    = (unsigned*)alloc(OVFCAP * sizeof(unsigned));
    int*            bcnt   = (int*)alloc(NB * P1B * sizeof(int));
    unsigned short* erow   = (unsigned short*)alloc((size_t)NN * CAP * sizeof(unsigned short));
    // overlay: buckets (pass1/pass2 only) and z (gemm onward) share memory
    size_t buckets_bytes = (size_t)NB * P1B * RCAP * sizeof(unsigned);   // 6.0 MB
    size_t z_bytes       = (size_t)NN * FDIM * 2;                        // 6.4 MB
    char* overlay = alloc(buckets_bytes > z_bytes ? buckets_bytes : z_bytes);
    unsigned* buckets = (unsigned*)overlay;
    unsigned* z       = (unsigned*)overlay;

    k_part  <<<P1B, 256, 0, stream>>>(row4, col4, buckets, bcnt, cnt, ovf, ovfcnt);
    k_fill  <<<NB * P1B, 256, 0, stream>>>(buckets, bcnt, cnt, erow, ovf, ovfcnt);
    k_gemm  <<<(NN + 63) / 64, 256, 0, stream>>>(x, W_w, cnt, z, NN);
    k_gather<<<NB * ((NPX + 3) / 4), 256, 0, stream>>>(cnt, erow, (const uint4*)z, W_b,
                                                       ovf, ovfcnt, out);
}

// Round 10
// 104.963 us; speedup vs baseline: 3.0045x; 1.0159x over previous
//
#include <hip/hip_runtime.h>

#define NN 50000
#define NE 800000
#define FDIM 64
#define NB 8          // coarse buckets == XCDs
#define P1B 192       // pass-1 blocks (block-private regions)
#define RCAP 1024     // per (bucket, block) region capacity
#define CAP 64        // per-node erow slots (max degree ~45 for Poisson(16))
#define OVFCAP 16384
#define NPX 6250      // nodes per XCD range (50000/8)
#define GEMMB ((NN + 63) / 64)   // 782 gemm blocks

typedef float f32x4 __attribute__((ext_vector_type(4)));

__device__ __forceinline__ unsigned rne_bf16(float f) {
    unsigned u = __float_as_uint(f);
    return (u + 0x7fffu + ((u >> 16) & 1u)) >> 16;
}

// ---- fused pass 1: blocks [0,P1B) partition edges; blocks [P1B,..) GEMM ----
// Partition also zeroes cnt/ovfcnt. GEMM writes UNSCALED bf16 z = x @ W^T
// (the rsqrt(deg) scales are applied per-edge in k_gather), so it has no
// dependency on cnt and can share this dispatch.
__global__ __launch_bounds__(256) void k_part_gemm(
        const int4* __restrict__ row4, const int4* __restrict__ col4,
        unsigned* __restrict__ buckets, int* __restrict__ bcnt,
        int* __restrict__ cnt, unsigned* __restrict__ ovf, int* __restrict__ ovfcnt,
        const float* __restrict__ x, const float* __restrict__ W,
        unsigned* __restrict__ z) {
    if (blockIdx.x < P1B) {
        // ---------------- partition ----------------
        int gid = blockIdx.x * 256 + threadIdx.x;
        for (int i = gid; i < NN; i += P1B * 256) cnt[i] = 0;
        if (gid == 0) *ovfcnt = 0;

        __shared__ int lcnt[NB];
        if (threadIdx.x < NB) lcnt[threadIdx.x] = 0;
        __syncthreads();
        const int E4 = NE / 4;
        for (int i = gid; i < E4; i += P1B * 256) {
            int4 r4 = row4[i];
            int4 c4 = col4[i];
            int rr[4] = {r4.x, r4.y, r4.z, r4.w};
            int cc[4] = {c4.x, c4.y, c4.z, c4.w};
#pragma unroll
            for (int t = 0; t < 4; ++t) {
                int c = cc[t];
                int b = (int)(((unsigned long long)(unsigned)c * 687195ull) >> 32); // c/6250
                unsigned pk = ((unsigned)rr[t] << 16) | (unsigned)c;
                int slot = atomicAdd(&lcnt[b], 1);             // LDS atomic
                if (slot < RCAP)
                    buckets[(size_t)(b * P1B + blockIdx.x) * RCAP + slot] = pk;
                else {                                         // impossible, guarded
                    int o = atomicAdd(ovfcnt, 1);
                    if (o < OVFCAP) ovf[o] = pk;
                }
            }
        }
        __syncthreads();
        if (threadIdx.x < NB)
            bcnt[threadIdx.x * P1B + blockIdx.x] = min(lcnt[threadIdx.x], RCAP);
    } else {
        // ---------------- GEMM tile ----------------
        __shared__ float Xl[64][68];
        __shared__ float Wt[64][68];   // Wt[k][o]

        for (int i = threadIdx.x; i < FDIM * FDIM; i += 256) {
            int o = i >> 6, k = i & 63;
            Wt[k][o] = W[i];
        }
        int tile = (int)(blockIdx.x - P1B) * 64;
        for (int i = threadIdx.x; i < 64 * 16; i += 256) {
            int r = i >> 4, c4 = i & 15;
            int gr = tile + r;
            f32x4 v = (gr < NN) ? __builtin_nontemporal_load(&((const f32x4*)x)[gr * 16 + c4])
                                : (f32x4){0.f, 0.f, 0.f, 0.f};
            *(f32x4*)&Xl[r][c4 * 4] = v;
        }
        __syncthreads();

        int tr = threadIdx.x >> 4;
        int tc = threadIdx.x & 15;

        float acc[4][4] = {};
#pragma unroll
        for (int k4 = 0; k4 < 16; ++k4) {
            f32x4 a[4], b[4];
#pragma unroll
            for (int i = 0; i < 4; ++i)
                a[i] = *(const f32x4*)&Xl[tr * 4 + i][k4 * 4];
#pragma unroll
            for (int kk = 0; kk < 4; ++kk)
                b[kk] = *(const f32x4*)&Wt[k4 * 4 + kk][tc * 4];
#pragma unroll
            for (int i = 0; i < 4; ++i) {
#pragma unroll
                for (int jj = 0; jj < 4; ++jj) {
                    acc[i][jj] += a[i].x * b[0][jj] + a[i].y * b[1][jj]
                                + a[i].z * b[2][jj] + a[i].w * b[3][jj];
                }
            }
        }

#pragma unroll
        for (int i = 0; i < 4; ++i) {
            int gr = tile + tr * 4 + i;
            if (gr < NN) {
                unsigned u01 = rne_bf16(acc[i][0]) | (rne_bf16(acc[i][1]) << 16);
                unsigned u23 = rne_bf16(acc[i][2]) | (rne_bf16(acc[i][3]) << 16);
                ((uint2*)z)[gr * 16 + tc] = make_uint2(u01, u23);
            }
        }
    }
}

// ---- pass 2: XCD-local degree count + fixed-capacity erow fill -------------
__global__ __launch_bounds__(256) void k_fill(const unsigned* __restrict__ buckets,
                                              const int* __restrict__ bcnt,
                                              int* __restrict__ cnt,
                                              unsigned short* __restrict__ erow,
                                              unsigned* __restrict__ ovf,
                                              int* __restrict__ ovfcnt) {
    int k  = blockIdx.x & (NB - 1);    // bucket == (assumed) XCD of this block
    int b1 = blockIdx.x >> 3;
    int m  = bcnt[k * P1B + b1];
    const unsigned* reg = buckets + (size_t)(k * P1B + b1) * RCAP;
    for (int i = threadIdx.x; i < m; i += 256) {
        unsigned pk = reg[i];
        int c = (int)(pk & 0xffffu), r = (int)(pk >> 16);
        int p = atomicAdd(&cnt[c], 1);                     // doubles as degree count
        if (p < CAP) erow[c * CAP + p] = (unsigned short)r;
        else {                                             // deg > 64: impossible, guarded
            int o = atomicAdd(ovfcnt, 1);
            if (o < OVFCAP) ovf[o] = pk;
        }
    }
}

// ---- gather: wave/node, 8 edges/iter, 8 lanes/edge; per-edge rsqrt scale ---
__global__ __launch_bounds__(256) void k_gather(
        const int* __restrict__ cnt, const unsigned short* __restrict__ erow,
        const uint4* __restrict__ z4, const float* __restrict__ bias,
        const unsigned* __restrict__ ovf, const int* __restrict__ ovfcnt,
        float* __restrict__ out) {
    int lane = threadIdx.x & 63;
    int wv   = threadIdx.x >> 6;
    int xk   = blockIdx.x & 7;          // node range == (assumed) XCD
    int sub  = blockIdx.x >> 3;
    int loc  = sub * 4 + wv;
    if (loc >= NPX) return;
    int node = xk * NPX + loc;

    int d  = cnt[node];
    int dc = min(d, CAP);
    int grp = lane >> 3, sl = lane & 7;
    int idx = (int)erow[node * CAP + lane];   // slots >= dc are garbage, masked below

    float a0=0,a1=0,a2=0,a3=0,a4=0,a5=0,a6=0,a7=0;
    int octets = (dc + 7) >> 3;
    for (int j = 0; j < octets; ++j) {
        int ei = j * 8 + grp;
        int rr = __shfl(idx, ei, 64);          // uniform control flow for shfl
        if (ei < dc) {                          // exec-masked
            int dr = cnt[rr];                   // 4B broadcast within group, L2-hot
            float sr = (dr > 0) ? rsqrtf((float)dr) : 0.f;
            uint4 u = z4[rr * 8 + sl];
            a0 += sr * __uint_as_float(u.x << 16);
            a1 += sr * __uint_as_float(u.x & 0xffff0000u);
            a2 += sr * __uint_as_float(u.y << 16);
            a3 += sr * __uint_as_float(u.y & 0xffff0000u);
            a4 += sr * __uint_as_float(u.z << 16);
            a5 += sr * __uint_as_float(u.z & 0xffff0000u);
            a6 += sr * __uint_as_float(u.w << 16);
            a7 += sr * __uint_as_float(u.w & 0xffff0000u);
        }
    }

    // overflow drain (impossible path, kept for strict correctness)
    int ovn = min(*ovfcnt, OVFCAP);
    if (ovn > 0) {
        for (int i = 0; i < ovn; ++i) {
            unsigned pk = ovf[i];
            if ((int)(pk & 0xffffu) == node && grp == 0) {
                int rr = (int)(pk >> 16);
                int dr = cnt[rr];
                float sr = (dr > 0) ? rsqrtf((float)dr) : 0.f;
                uint4 u = z4[rr * 8 + sl];
                a0 += sr * __uint_as_float(u.x << 16);
                a1 += sr * __uint_as_float(u.x & 0xffff0000u);
                a2 += sr * __uint_as_float(u.y << 16);
                a3 += sr * __uint_as_float(u.y & 0xffff0000u);
                a4 += sr * __uint_as_float(u.z << 16);
                a5 += sr * __uint_as_float(u.z & 0xffff0000u);
                a6 += sr * __uint_as_float(u.w << 16);
                a7 += sr * __uint_as_float(u.w & 0xffff0000u);
            }
        }
    }

#pragma unroll
    for (int m = 8; m <= 32; m <<= 1) {
        a0 += __shfl_xor(a0, m, 64); a1 += __shfl_xor(a1, m, 64);
        a2 += __shfl_xor(a2, m, 64); a3 += __shfl_xor(a3, m, 64);
        a4 += __shfl_xor(a4, m, 64); a5 += __shfl_xor(a5, m, 64);
        a6 += __shfl_xor(a6, m, 64); a7 += __shfl_xor(a7, m, 64);
    }
    if (grp == 0) {
        float sc = (d > 0) ? rsqrtf((float)d) : 0.f;
        f32x4 b0 = ((const f32x4*)bias)[sl * 2];
        f32x4 b1 = ((const f32x4*)bias)[sl * 2 + 1];
        f32x4 o0 = {sc*a0+b0.x, sc*a1+b0.y, sc*a2+b0.z, sc*a3+b0.w};
        f32x4 o1 = {sc*a4+b1.x, sc*a5+b1.y, sc*a6+b1.z, sc*a7+b1.w};
        __builtin_nontemporal_store(o0, &((f32x4*)out)[node * 16 + sl * 2]);
        __builtin_nontemporal_store(o1, &((f32x4*)out)[node * 16 + sl * 2 + 1]);
    }
}

// ---------------------------------------------------------------------------
extern "C" void kernel_launch(void* const* d_in, const int* in_sizes, int n_in,
                              void* d_out, int out_size, void* d_ws, size_t ws_size,
                              hipStream_t stream) {
    const float* x   = (const float*)d_in[0];
    // d_in[1] = x0 (unused: use_init=False)
    const int*   ei  = (const int*)d_in[2];   // harness stores integers as int32
    const float* W_w = (const float*)d_in[3];
    const float* W_b = (const float*)d_in[4];
    float*       out = (float*)d_out;

    const int4* row4 = (const int4*)ei;          // edge_index[0]
    const int4* col4 = (const int4*)(ei + NE);   // edge_index[1]

    char* p = (char*)d_ws;
    auto alloc = [&](size_t bytes) {
        char* r = p;
        p += (bytes + 255) & ~(size_t)255;
        return r;
    };
    int*            cnt    = (int*)alloc(NN * sizeof(int));
    int*            ovfcnt = (int*)alloc(256);
    unsigned*       ovf    = (unsigned*)alloc(OVFCAP * sizeof(unsigned));
    int*            bcnt   = (int*)alloc(NB * P1B * sizeof(int));
    unsigned short* erow   = (unsigned short*)alloc((size_t)NN * CAP * sizeof(unsigned short));
    // NOTE: buckets and z no longer overlay (part and gemm run concurrently)
    unsigned*       buckets = (unsigned*)alloc((size_t)NB * P1B * RCAP * sizeof(unsigned)); // 6.0 MB
    unsigned*       z       = (unsigned*)alloc((size_t)NN * FDIM * 2);                      // 6.4 MB

    k_part_gemm<<<P1B + GEMMB, 256, 0, stream>>>(row4, col4, buckets, bcnt, cnt,
                                                 ovf, ovfcnt, x, W_w, z);
    k_fill  <<<NB * P1B, 256, 0, stream>>>(buckets, bcnt, cnt, erow, ovf, ovfcnt);
    k_gather<<<NB * ((NPX + 3) / 4), 256, 0, stream>>>(cnt, erow, (const uint4*)z, W_b,
                                                       ovf, ovfcnt, out);
}